// Round 12
// baseline (456.694 us; speedup 1.0000x reference)
//
#include <hip/hip_runtime.h>

#define CC 19
#define NPOS 361
#define NPAD 384
#define DIM 256
#define TKEY 32
#define NTILES 12

// LDS (bytes): bufx0/bufx1 32x264 bf16 double-buffered x tile = 33792 total.
// Epilogue reuse: bufx0 = AO (bf16), bufx1 = sL (first 1KB) then proj T.
// 2 blocks/CU -> 67.6KB of 160KB.
#define LDS_BYTES 33792

using bf16x8 = __attribute__((ext_vector_type(8))) short;
using f16x4  = __attribute__((ext_vector_type(4))) _Float16;
using floatx4 = __attribute__((ext_vector_type(4))) float;
using uintx2 = __attribute__((ext_vector_type(2))) unsigned int;

__device__ __forceinline__ unsigned short f2bf(float f) {
  unsigned u = __builtin_bit_cast(unsigned, f);
  u += 0x7fffu + ((u >> 16) & 1u);
  return (unsigned short)(u >> 16);
}

__device__ __forceinline__ f16x4 pack4h(float a, float b, float c2, float d) {
  const auto h01 = __builtin_amdgcn_cvt_pkrtz(a, b);
  const auto h23 = __builtin_amdgcn_cvt_pkrtz(c2, d);
  uintx2 uv = {__builtin_bit_cast(unsigned, h01), __builtin_bit_cast(unsigned, h23)};
  return __builtin_bit_cast(f16x4, uv);
}

// fused conversion: x (zero-padded 361->384 rows) + all weights, f32 -> bf16
// (R8 lesson: inline conversion in the hot kernel raises the liveset -> spills)
__global__ void conv_all_kernel(const float* __restrict__ x,
                                const float* __restrict__ w_in,
                                const float* __restrict__ w_out,
                                const float* __restrict__ w_fuse,
                                unsigned short* __restrict__ ws) {
  const int j = blockIdx.x * 256 + threadIdx.x;
  float4 v = make_float4(0.f, 0.f, 0.f, 0.f);
  unsigned short* dst;
  if (j < 786432) {
    const int row = j >> 6;
    const int off = (j & 63) << 2;
    const int b = row / NPAD;
    const int r = row - b * NPAD;
    if (r < NPOS) v = *(const float4*)&x[(b * NPOS + r) * DIM + off];
    dst = &ws[row * DIM + off];
  } else if (j < 1720320) {
    const int k = j - 786432;
    v = *(const float4*)&w_in[k << 2];
    dst = &ws[3145728 + (k << 2)];
  } else if (j < 2031616) {
    const int k = j - 1720320;
    v = *(const float4*)&w_out[k << 2];
    dst = &ws[6881280 + (k << 2)];
  } else {
    const int k = j - 2031616;
    v = *(const float4*)&w_fuse[k << 2];
    dst = &ws[8126464 + (k << 2)];
  }
  ushort4 o;
  o.x = f2bf(v.x); o.y = f2bf(v.y); o.z = f2bf(v.z); o.w = f2bf(v.w);
  *(ushort4*)dst = o;
}

// launch_bounds (512,4): 128-unified-reg cap -> 4 waves/SIMD, 2 blocks/CU.
// This is only safe now: weights are STREAMED from L2 (R5/R6 measured the
// register-resident slabs were worth ~0), dropping the liveset to ~115.
// Spill tripwire: WRITE_SIZE (clean = ~11.5 MB; spills = 3x+ -> revert).
__launch_bounds__(512, 4)
__global__ void cgca_kernel(const float* __restrict__ xf,
                            const float* __restrict__ b_in,
                            const float* __restrict__ b_out,
                            const float* __restrict__ b_fuse,
                            const unsigned short* __restrict__ xbf,
                            const unsigned short* __restrict__ wibf,
                            const unsigned short* __restrict__ wobf,
                            const unsigned short* __restrict__ wfbf,
                            float* __restrict__ out) {
  // XCD-aware swizzle: same channel's 32 batches contiguous on one XCD
  // (matters more now that weights re-stream from L2 every tile).
  const int bid = blockIdx.x;
  const int xcd = bid & 7;
  const int slot = bid >> 3;
  int c, b;
  if (slot < 64) {
    c = ((slot >> 5) << 3) + xcd;   // channels 0..15
    b = slot & 31;
  } else {
    const int widx = ((slot - 64) << 3) + xcd;  // 0..95
    c = 16 + (widx >> 5);           // channels 16..18
    b = widx & 31;
  }

  const int tid = threadIdx.x;
  const int w = tid >> 6;        // wave 0..7 == head index
  const int lane = tid & 63;
  const int quad = lane >> 4;
  const int l16 = lane & 15;
  const int eh = w * 32;

  extern __shared__ char smem[];
  unsigned short* bufx0 = (unsigned short*)(smem);
  unsigned short* bufx1 = (unsigned short*)(smem + 16896);
  float* sL = (float*)(smem + 16896);  // 8 waves x 32 floats; dead before T written

  const float scale = 0.17677669529663687f;  // 1/sqrt(32)
  const floatx4 fzero = {0.f, 0.f, 0.f, 0.f};

  // hoisted small biases (18 f32 regs)
  float bq[2][4], bk[2][4], bV[2];
#pragma unroll
  for (int m4 = 0; m4 < 2; ++m4) {
    const float4 q4 = *(const float4*)&b_in[c * 768 + eh + m4 * 16 + quad * 4];
    bq[m4][0] = q4.x; bq[m4][1] = q4.y; bq[m4][2] = q4.z; bq[m4][3] = q4.w;
    const float4 k4 = *(const float4*)&b_in[c * 768 + 256 + eh + m4 * 16 + quad * 4];
    bk[m4][0] = k4.x; bk[m4][1] = k4.y; bk[m4][2] = k4.z; bk[m4][3] = k4.w;
    bV[m4] = b_in[c * 768 + 512 + eh + m4 * 16 + l16];
  }

  // ---------------- Q phase: qf[mt][echunk] = B-frag of transposed scores.
  // MFMA(wQ as A, xq as B) -> D[m=e][n=q]: lane q=l16 (col), e=quad*4+r (row).
  // wQ fragments streamed from L2 inside the k-loop (not register-resident).
  f16x4 qf[2][2];
#pragma unroll
  for (int mt = 0; mt < 2; ++mt) {
    const int xrow = b * NPAD + c * CC + mt * 16 + l16;  // zero-padded rows
    bf16x8 xq[8];
#pragma unroll
    for (int k = 0; k < 8; ++k)
      xq[k] = *(const bf16x8*)&xbf[xrow * DIM + k * 32 + quad * 8];
#pragma unroll
    for (int m4 = 0; m4 < 2; ++m4) {
      const unsigned short* wqp = &wibf[(c * 768 + eh + m4 * 16 + l16) * DIM + quad * 8];
      floatx4 acc = fzero;
#pragma unroll
      for (int k = 0; k < 8; ++k) {
        const bf16x8 wq = *(const bf16x8*)(wqp + k * 32);
        acc = __builtin_amdgcn_mfma_f32_16x16x32_bf16(wq, xq[k], acc, 0, 0, 0);
      }
      qf[mt][m4] = pack4h((acc[0] + bq[m4][0]) * scale, (acc[1] + bq[m4][1]) * scale,
                          (acc[2] + bq[m4][2]) * scale, (acc[3] + bq[m4][3]) * scale);
    }
  }

  // stage x tile 0 -> bufx0
#pragma unroll
  for (int it = 0; it < 2; ++it) {
    const int cc2 = tid + it * 512;
    const int row = cc2 >> 5;
    const int col = (cc2 & 31) * 8;
    *(bf16x8*)&bufx0[row * 264 + col] = *(const bf16x8*)&xbf[(b * NPAD + row) * DIM + col];
  }

  floatx4 o_acc[2][2];           // [mt][echunk], D[m=q][n=e]: q=quad*4+r, e=l16
  float lsum[2] = {0.f, 0.f};    // per-lane partial denom (q=l16, keys of this quad)
#pragma unroll
  for (int mt = 0; mt < 2; ++mt)
#pragma unroll
    for (int ne = 0; ne < 2; ++ne) o_acc[mt][ne] = fzero;

  const unsigned short* wkbase = &wibf[(c * 768 + 256 + eh + l16) * DIM + quad * 8];
  const unsigned short* wvbase = &wibf[(c * 768 + 512 + eh + l16) * DIM + quad * 8];

  __syncthreads();  // x(0) staged

  for (int t = 0; t < NTILES; ++t) {
    const int t0 = t * TKEY;
    unsigned short* bx  = (t & 1) ? bufx1 : bufx0;
    unsigned short* bxn = (t & 1) ? bufx0 : bufx1;

    // stage x(t+1) -> other buffer (its readers are past this iteration's barrier)
    if (t + 1 < NTILES) {
#pragma unroll
      for (int it = 0; it < 2; ++it) {
        const int cc2 = tid + it * 512;
        const int row = cc2 >> 5;
        const int col = (cc2 & 31) * 8;
        *(bf16x8*)&bxn[row * 264 + col] =
            *(const bf16x8*)&xbf[(b * NPAD + t0 + TKEY + row) * DIM + col];
      }
    }

    // ---------------- proj pass 1: K. aK[echunk][keytile] = MFMA(wK, x):
    // lane key=l16, e=quad*4+r  ->  kf = A-frag of transposed scores.
    f16x4 kf[2][2];  // [keytile][echunk]
    {
      floatx4 aK[2][2];
#pragma unroll
      for (int i = 0; i < 2; ++i)
#pragma unroll
        for (int j = 0; j < 2; ++j) aK[i][j] = fzero;
#pragma unroll
      for (int k = 0; k < 8; ++k) {
        bf16x8 xfr[2], wkf[2];
#pragma unroll
        for (int n4 = 0; n4 < 2; ++n4) {
          xfr[n4] = *(const bf16x8*)&bx[(n4 * 16 + l16) * 264 + k * 32 + quad * 8];
          wkf[n4] = *(const bf16x8*)(wkbase + (n4 * 16) * DIM + k * 32);
        }
#pragma unroll
        for (int m4 = 0; m4 < 2; ++m4)
#pragma unroll
          for (int n4 = 0; n4 < 2; ++n4)
            aK[m4][n4] =
                __builtin_amdgcn_mfma_f32_16x16x32_bf16(wkf[m4], xfr[n4], aK[m4][n4], 0, 0, 0);
      }
#pragma unroll
      for (int kt = 0; kt < 2; ++kt)
#pragma unroll
        for (int ec = 0; ec < 2; ++ec)
          kf[kt][ec] = pack4h(aK[ec][kt][0] + bk[ec][0], aK[ec][kt][1] + bk[ec][1],
                              aK[ec][kt][2] + bk[ec][2], aK[ec][kt][3] + bk[ec][3]);
    }

    // ---------------- proj pass 2: V. aV[keytile][echunk] = MFMA(x, wV):
    // lane e=l16, key=quad*4+r  ->  vf = B-frag of PV.
    f16x4 vf[2][2];  // [keytile][echunk]
    {
      floatx4 aV[2][2];
#pragma unroll
      for (int i = 0; i < 2; ++i)
#pragma unroll
        for (int j = 0; j < 2; ++j) aV[i][j] = fzero;
#pragma unroll
      for (int k = 0; k < 8; ++k) {
        bf16x8 xfr[2], wvf[2];
#pragma unroll
        for (int n4 = 0; n4 < 2; ++n4) {
          xfr[n4] = *(const bf16x8*)&bx[(n4 * 16 + l16) * 264 + k * 32 + quad * 8];
          wvf[n4] = *(const bf16x8*)(wvbase + (n4 * 16) * DIM + k * 32);
        }
#pragma unroll
        for (int m4 = 0; m4 < 2; ++m4)
#pragma unroll
          for (int n4 = 0; n4 < 2; ++n4)
            aV[n4][m4] =
                __builtin_amdgcn_mfma_f32_16x16x32_bf16(xfr[n4], wvf[m4], aV[n4][m4], 0, 0, 0);
      }
#pragma unroll
      for (int kt = 0; kt < 2; ++kt)
#pragma unroll
        for (int ec = 0; ec < 2; ++ec)
          vf[kt][ec] = pack4h(aV[kt][ec][0] + bV[ec], aV[kt][ec][1] + bV[ec],
                              aV[kt][ec][2] + bV[ec], aV[kt][ec][3] + bV[ec]);
    }
    __syncthreads();  // the ONE barrier: all reads of bx done; rest is register-only

    // ---------------- scores (transposed) + mask + exp + PV, all in registers
#pragma unroll
    for (int mt = 0; mt < 2; ++mt) {
      const unsigned q = (unsigned)(mt * 16 + l16);
      f16x4 pf[2];
#pragma unroll
      for (int kt = 0; kt < 2; ++kt) {
        floatx4 s = __builtin_amdgcn_mfma_f32_16x16x16f16(kf[kt][0], qf[mt][0], fzero, 0, 0, 0);
        s = __builtin_amdgcn_mfma_f32_16x16x16f16(kf[kt][1], qf[mt][1], s, 0, 0, 0);
        // lane: q=l16 (col), key = t0 + kt*16 + quad*4 + r (row)
        const int kbase = t0 + kt * 16 + quad * 4;
        float p[4];
#pragma unroll
        for (int r = 0; r < 4; ++r) {
          const int kabs = kbase + r;
          const unsigned ki = ((unsigned)kabs * 110377u) >> 21;  // kabs/19, kabs<=383
          const unsigned kj = (unsigned)kabs - ki * 19u;
          const bool ok = (kabs < NPOS) &&
                          (ki == (unsigned)c || kj == (unsigned)c || ki == q || kj == q);
          p[r] = ok ? __expf(s[r]) : 0.f;
        }
        lsum[mt] += (p[0] + p[1]) + (p[2] + p[3]);
        pf[kt] = pack4h(p[0], p[1], p[2], p[3]);
      }
#pragma unroll
      for (int kt = 0; kt < 2; ++kt)
#pragma unroll
        for (int ne = 0; ne < 2; ++ne)
          o_acc[mt][ne] =
              __builtin_amdgcn_mfma_f32_16x16x16f16(pf[kt], vf[kt][ne], o_acc[mt][ne], 0, 0, 0);
    }
  }  // tile loop

  // ---------------- denom: reduce lsum across quads (q=l16 fixed), publish per wave
#pragma unroll
  for (int mt = 0; mt < 2; ++mt) {
    lsum[mt] += __shfl_xor(lsum[mt], 16);
    lsum[mt] += __shfl_xor(lsum[mt], 32);
  }
  if (lane < 16) {
    sL[w * 32 + lane] = lsum[0];
    sL[w * 32 + 16 + lane] = lsum[1];
  }
  // wave-local LDS round-trip (lgkmcnt-ordered), no barrier needed
  float invl[2][4];
#pragma unroll
  for (int mt = 0; mt < 2; ++mt)
#pragma unroll
    for (int r = 0; r < 4; ++r)
      invl[mt][r] = 1.f / sL[w * 32 + mt * 16 + quad * 4 + r];

  // ---------------- AO -> bufx0 (bf16): row q = mt*16+quad*4+r, col = eh+ne*16+l16
#pragma unroll
  for (int mt = 0; mt < 2; ++mt)
#pragma unroll
    for (int ne = 0; ne < 2; ++ne)
#pragma unroll
      for (int r = 0; r < 4; ++r)
        bufx0[(mt * 16 + quad * 4 + r) * 264 + eh + ne * 16 + l16] =
            f2bf(o_acc[mt][ne][r] * invl[mt][r]);
  __syncthreads();

  // ---------------- GEMM1: proj = AO @ w_out^T + b_out -> bufx1 (bf16)
#pragma unroll
  for (int mt = 0; mt < 2; ++mt) {
    bf16x8 a8[8];
#pragma unroll
    for (int k = 0; k < 8; ++k)
      a8[k] = *(const bf16x8*)&bufx0[(mt * 16 + l16) * 264 + k * 32 + quad * 8];
#pragma unroll
    for (int nt2 = 0; nt2 < 2; ++nt2) {
      const int e0 = w * 32 + nt2 * 16;
      floatx4 acc = fzero;
#pragma unroll
      for (int k = 0; k < 8; ++k) {
        bf16x8 b8 = *(const bf16x8*)&wobf[(c * 256 + e0 + l16) * DIM + k * 32 + quad * 8];
        acc = __builtin_amdgcn_mfma_f32_16x16x32_bf16(a8[k], b8, acc, 0, 0, 0);
      }
      const float bias = b_out[c * 256 + e0 + l16];
#pragma unroll
      for (int r = 0; r < 4; ++r)
        bufx1[(mt * 16 + quad * 4 + r) * 264 + e0 + l16] = f2bf(acc[r] + bias);
    }
  }
  __syncthreads();

  // ---------------- GEMM2: out = proj @ w_fuse^T + b_fuse + x
#pragma unroll
  for (int mt = 0; mt < 2; ++mt) {
    bf16x8 a8[8];
#pragma unroll
    for (int k = 0; k < 8; ++k)
      a8[k] = *(const bf16x8*)&bufx1[(mt * 16 + l16) * 264 + k * 32 + quad * 8];
#pragma unroll
    for (int nt2 = 0; nt2 < 2; ++nt2) {
      const int e0 = w * 32 + nt2 * 16;
      floatx4 acc = fzero;
#pragma unroll
      for (int k = 0; k < 8; ++k) {
        bf16x8 b8 = *(const bf16x8*)&wfbf[(e0 + l16) * DIM + k * 32 + quad * 8];
        acc = __builtin_amdgcn_mfma_f32_16x16x32_bf16(a8[k], b8, acc, 0, 0, 0);
      }
      const float bfu = b_fuse[e0 + l16];
#pragma unroll
      for (int r = 0; r < 4; ++r) {
        const int row = mt * 16 + quad * 4 + r;
        if (row < CC) {
          const int gp = (b * NPOS + c * CC + row) * DIM + e0 + l16;
          out[gp] = acc[r] + bfu + xf[gp];
        }
      }
    }
  }
}

extern "C" void kernel_launch(void* const* d_in, const int* in_sizes, int n_in,
                              void* d_out, int out_size, void* d_ws, size_t ws_size,
                              hipStream_t stream) {
  const float* x      = (const float*)d_in[0];
  const float* w_in   = (const float*)d_in[1];
  const float* b_in   = (const float*)d_in[2];
  const float* w_out  = (const float*)d_in[3];
  const float* b_out  = (const float*)d_in[4];
  const float* w_fuse = (const float*)d_in[5];
  const float* b_fuse = (const float*)d_in[6];
  float* out = (float*)d_out;

  if (ws_size < (size_t)16384000) return;  // 16.38 MB bf16 scratch (validated bound)

  unsigned short* ws = (unsigned short*)d_ws;
  unsigned short* x_bf  = ws;              // 32*384*256   = 3,145,728
  unsigned short* wi_bf = ws + 3145728;    // 19*768*256   = 3,735,552
  unsigned short* wo_bf = ws + 6881280;    // 19*256*256   = 1,245,184
  unsigned short* wf_bf = ws + 8126464;    // 256*256      = 65,536

  conv_all_kernel<<<8000, 256, 0, stream>>>(x, w_in, w_out, w_fuse, ws);

  (void)hipFuncSetAttribute((const void*)cgca_kernel,
                            hipFuncAttributeMaxDynamicSharedMemorySize, LDS_BYTES);
  cgca_kernel<<<608, 512, LDS_BYTES, stream>>>(x, b_in, b_out, b_fuse, x_bf, wi_bf,
                                               wo_bf, wf_bf, out);
}